// Round 14
// baseline (353.350 us; speedup 1.0000x reference)
//
#include <hip/hip_runtime.h>
#include <hip/hip_fp16.h>
#include <math.h>

#define NN 10000
#define NE 100000
#define BN_EPS 1e-5f
#define GRID 256
#define BLK 320

// Lessons (measured):
//  R0:212  R7 bf16-G:203  R10 pk-f16 atomics:191  R13 occupancy:187.
//  Intrinsic work sums to ~40-50us => ~130us is per-stage drain/ramp
//  (9 serial kernel boundaries). R4's coop-launch megakernel failed at
//  LAUNCH (graph-capture tripwire), not a race. R14: normal-launch
//  megakernel, hand-rolled spin barrier, GRID=256 (1 block/CU => co-residency
//  guaranteed), R13 phase bodies verbatim.

__device__ __forceinline__ unsigned short f2bf(float f) {
  unsigned int u = __float_as_uint(f);
  u += 0x7FFF + ((u >> 16) & 1);
  return (unsigned short)(u >> 16);
}
__device__ __forceinline__ float bf2f(unsigned short h) {
  return __uint_as_float(((unsigned int)h) << 16);
}

struct P {
  const float *x; const int *ei; const float *ea; const int *batch;
  const float *w0, *b0, *root0, *bias0, *g0, *be0;
  const float *w1, *b1, *root1, *bias1, *g1, *be1;
  const float *s_w, *s_b, *t_w, *t_b;
  float *out;
  unsigned short *G0h, *G1h; __half *h0h, *h1h;
  float *x1, *x2, *st0, *st1, *wT0, *wT1, *wstT;
  int2 *ei2; unsigned int *bar;
};

// Grid barrier: monotonic counter, device-scope atomics, agent fences.
// Safe because GRID=256 blocks are all co-resident (1 block/CU).
__device__ __forceinline__ void gbar(unsigned int* bar) {
  __syncthreads();
  if (threadIdx.x == 0) {
    __threadfence();                          // release: flush stores (L2 wb)
    unsigned t = atomicAdd(bar, 1u);
    unsigned goal = (t / GRID + 1u) * GRID;
    while (atomicAdd(bar, 0u) < goal) __builtin_amdgcn_s_sleep(4);
    __threadfence();                          // acquire: invalidate for fresh loads
  }
  __syncthreads();
}

__global__ __launch_bounds__(BLK, 2) void mega(P p)
{
  const int tid = threadIdx.x;
  const int blk = blockIdx.x;
  const int gid = blk * BLK + tid;
  const int gsz = GRID * BLK;
  __shared__ float l1[BLK], l2[BLK];
  __shared__ float sc[64], sh[64];

  // ================= P0: prep (ei2, wT0, wT1, wstT, zeros) =================
  for (int e = gid; e < NE; e += gsz)
    p.ei2[e] = make_int2(p.ei[e], p.ei[NE + e]);
  for (int idx = gid; idx < 16 * 320; idx += gsz) {
    int i = idx / 320, c = idx - i * 320;
    float v;
    if (c < 256)      v = p.w0[(i * 32 + (c & 31)) * 8 + (c >> 5)];
    else if (c < 288) v = p.b0[i * 32 + (c - 256)];
    else              v = p.root0[i * 32 + (c - 288)];
    p.wT0[idx] = v;
  }
  for (int idx = gid; idx < 32 * 640; idx += gsz) {
    int i = idx / 640, c = idx - i * 640;
    float v;
    if (c < 512)      v = p.w1[(i * 64 + (c & 63)) * 8 + (c >> 6)];
    else if (c < 576) v = p.b1[i * 64 + (c - 512)];
    else              v = p.root1[i * 64 + (c - 576)];
    p.wT1[idx] = v;
  }
  for (int idx = gid; idx < 64 * 256; idx += gsz) {
    int i = idx >> 8, o = idx & 255;
    p.wstT[idx] = (o < 128) ? p.s_w[o * 64 + i] : p.t_w[(o - 128) * 64 + i];
  }
  for (int idx = gid; idx < 64 * 128; idx += gsz) p.out[idx] = 0.f;
  if (gid < 64)  p.st0[gid] = 0.f;
  if (gid < 128) p.st1[gid] = 0.f;
  gbar(p.bar);

  // ================= P1: node0 (R13 body; 1000 virtual blocks) =============
  {
    int c = tid;
    float wc[16];
#pragma unroll
    for (int i = 0; i < 16; ++i) wc[i] = p.wT0[i * 320 + c];
    float bi = (c >= 288) ? p.bias0[c - 288] : 0.f;
    for (int vb = blk; vb < 1000; vb += GRID) {
      int n0 = vb * 10;
      for (int n = n0; n < n0 + 10; n += 2) {
        const float4* xa = (const float4*)(p.x + n * 16);
        float a0 = 0.f, a1 = 0.f;
#pragma unroll
        for (int q = 0; q < 4; ++q) {
          float4 v0 = xa[q], v1 = xa[q + 4];
          a0 = fmaf(v0.x, wc[4*q+0], a0); a1 = fmaf(v1.x, wc[4*q+0], a1);
          a0 = fmaf(v0.y, wc[4*q+1], a0); a1 = fmaf(v1.y, wc[4*q+1], a1);
          a0 = fmaf(v0.z, wc[4*q+2], a0); a1 = fmaf(v1.z, wc[4*q+2], a1);
          a0 = fmaf(v0.w, wc[4*q+3], a0); a1 = fmaf(v1.w, wc[4*q+3], a1);
        }
        if (c < 288) {
          p.G0h[n * 288 + c]       = f2bf(a0);
          p.G0h[(n + 1) * 288 + c] = f2bf(a1);
        } else {
          p.h0h[n * 32 + (c - 288)]       = __float2half(a0 + bi);
          p.h0h[(n + 1) * 32 + (c - 288)] = __float2half(a1 + bi);
        }
      }
    }
  }
  gbar(p.bar);

  // ================= P2: edge0 (R13 body; 20 slots/block) ==================
  {
    int slot = tid >> 4;            // 0..19
    int oo = (tid & 15) * 2;
    for (int e = blk * 20 + slot; e < NE; e += GRID * 20) {
      int2 sd = p.ei2[e];
      const unsigned short* gr = p.G0h + sd.x * 288;
      const float4* ep = (const float4*)(p.ea + (size_t)e * 8);
      float4 e0 = ep[0], e1 = ep[1];
      float m0 = bf2f(gr[256 + oo]), m1 = bf2f(gr[256 + oo + 1]);
#pragma unroll
      for (int k = 0; k < 8; ++k) {
        ushort2 g2 = *(const ushort2*)(gr + k * 32 + oo);
        float ek = (k < 4) ? ((k==0)?e0.x:(k==1)?e0.y:(k==2)?e0.z:e0.w)
                           : ((k==4)?e1.x:(k==5)?e1.y:(k==6)?e1.z:e1.w);
        m0 = fmaf(ek, bf2f(g2.x), m0);
        m1 = fmaf(ek, bf2f(g2.y), m1);
      }
      unsafeAtomicAdd((__half2*)(p.h0h + sd.y * 32 + oo), __floats2half2_rn(m0, m1));
    }
  }
  gbar(p.bar);

  // ================= P3: stats<32> (10 row-groups of 32) ===================
  {
    const int C = 32, RPB = BLK / C;      // 10
    int col = tid % C, rg = tid / C;
    float s1 = 0.f, s2 = 0.f;
    for (int n = blk * RPB + rg; n < NN; n += GRID * RPB) {
      float v = __half2float(p.h0h[n * C + col]);
      s1 += v; s2 += v * v;
    }
    l1[tid] = s1; l2[tid] = s2;
    __syncthreads();
    if (tid < C) {
      for (int r = 1; r < RPB; ++r) { s1 += l1[r*C + tid]; s2 += l2[r*C + tid]; }
      unsafeAtomicAdd(&p.st0[tid], s1);
      unsafeAtomicAdd(&p.st0[C + tid], s2);
    }
  }
  gbar(p.bar);

  // ================= P4: x1 = relu(bn0(h0h)) -> f32 ========================
  {
    if (tid < 32) {
      float mu  = p.st0[tid] * (1.0f / NN);
      float var = p.st0[32 + tid] * (1.0f / NN) - mu * mu;
      float s   = p.g0[tid] * rsqrtf(var + BN_EPS);
      sc[tid] = s;
      sh[tid] = p.be0[tid] - mu * s;
    }
    __syncthreads();
    const int NV = NN * 16;
    for (int i = gid; i < NV; i += gsz) {
      __half2 hv = ((const __half2*)p.h0h)[i];
      int c0 = (i * 2) & 31;
      float vx = fmaxf(fmaf(__half2float(hv.x), sc[c0],     sh[c0]),     0.f);
      float vy = fmaxf(fmaf(__half2float(hv.y), sc[c0 + 1], sh[c0 + 1]), 0.f);
      ((float2*)p.x1)[i] = make_float2(vx, vy);
    }
  }
  gbar(p.bar);

  // ================= P5: node1 (R13 body; 1000 virtual blocks) =============
  {
    int t = tid;
    float wa[32], wb[32];
#pragma unroll
    for (int i = 0; i < 32; ++i) {
      float2 w2 = *(const float2*)(p.wT1 + i * 640 + 2 * t);
      wa[i] = w2.x; wb[i] = w2.y;
    }
    float bia = 0.f, bib = 0.f;
    if (t >= 288) { bia = p.bias1[2*(t-288)]; bib = p.bias1[2*(t-288)+1]; }
    for (int vb = blk; vb < 1000; vb += GRID) {
      int n0 = vb * 10;
      for (int n = n0; n < n0 + 10; n += 2) {
        const float4* xa = (const float4*)(p.x1 + n * 32);
        float a00 = 0.f, a01 = 0.f, a10 = 0.f, a11 = 0.f;
#pragma unroll
        for (int q = 0; q < 8; ++q) {
          float4 v0 = xa[q], v1 = xa[q + 8];
          a00 = fmaf(v0.x, wa[4*q+0], a00); a01 = fmaf(v0.x, wb[4*q+0], a01);
          a00 = fmaf(v0.y, wa[4*q+1], a00); a01 = fmaf(v0.y, wb[4*q+1], a01);
          a00 = fmaf(v0.z, wa[4*q+2], a00); a01 = fmaf(v0.z, wb[4*q+2], a01);
          a00 = fmaf(v0.w, wa[4*q+3], a00); a01 = fmaf(v0.w, wb[4*q+3], a01);
          a10 = fmaf(v1.x, wa[4*q+0], a10); a11 = fmaf(v1.x, wb[4*q+0], a11);
          a10 = fmaf(v1.y, wa[4*q+1], a10); a11 = fmaf(v1.y, wb[4*q+1], a11);
          a10 = fmaf(v1.z, wa[4*q+2], a10); a11 = fmaf(v1.z, wb[4*q+2], a11);
          a10 = fmaf(v1.w, wa[4*q+3], a10); a11 = fmaf(v1.w, wb[4*q+3], a11);
        }
        if (t < 288) {
          *(ushort2*)(p.G1h + n * 576 + 2*t)       = make_ushort2(f2bf(a00), f2bf(a01));
          *(ushort2*)(p.G1h + (n + 1) * 576 + 2*t) = make_ushort2(f2bf(a10), f2bf(a11));
        } else {
          int o = 2 * (t - 288);
          *(__half2*)(p.h1h + n * 64 + o)       = __floats2half2_rn(a00 + bia, a01 + bib);
          *(__half2*)(p.h1h + (n + 1) * 64 + o) = __floats2half2_rn(a10 + bia, a11 + bib);
        }
      }
    }
  }
  gbar(p.bar);

  // ================= P6: edge1 (R13 body; 10 slots/block) ==================
  {
    int slot = tid >> 5;            // 0..9
    int oo = (tid & 31) * 2;
    for (int e = blk * 10 + slot; e < NE; e += GRID * 10) {
      int2 sd = p.ei2[e];
      const unsigned short* gr = p.G1h + sd.x * 576;
      const float4* ep = (const float4*)(p.ea + (size_t)e * 8);
      float4 e0 = ep[0], e1 = ep[1];
      float m0 = bf2f(gr[512 + oo]), m1 = bf2f(gr[512 + oo + 1]);
#pragma unroll
      for (int k = 0; k < 8; ++k) {
        ushort2 g2 = *(const ushort2*)(gr + k * 64 + oo);
        float ek = (k < 4) ? ((k==0)?e0.x:(k==1)?e0.y:(k==2)?e0.z:e0.w)
                           : ((k==4)?e1.x:(k==5)?e1.y:(k==6)?e1.z:e1.w);
        m0 = fmaf(ek, bf2f(g2.x), m0);
        m1 = fmaf(ek, bf2f(g2.y), m1);
      }
      unsafeAtomicAdd((__half2*)(p.h1h + sd.y * 64 + oo), __floats2half2_rn(m0, m1));
    }
  }
  gbar(p.bar);

  // ================= P7: stats<64> (5 row-groups of 64) ====================
  {
    const int C = 64, RPB = BLK / C;      // 5
    int col = tid % C, rg = tid / C;
    float s1 = 0.f, s2 = 0.f;
    for (int n = blk * RPB + rg; n < NN; n += GRID * RPB) {
      float v = __half2float(p.h1h[n * C + col]);
      s1 += v; s2 += v * v;
    }
    l1[tid] = s1; l2[tid] = s2;
    __syncthreads();
    if (tid < C) {
      for (int r = 1; r < RPB; ++r) { s1 += l1[r*C + tid]; s2 += l2[r*C + tid]; }
      unsafeAtomicAdd(&p.st1[tid], s1);
      unsafeAtomicAdd(&p.st1[C + tid], s2);
    }
  }
  gbar(p.bar);

  // ================= P8: x2 = relu(bn1(h1h)) -> f32 ========================
  {
    if (tid < 64) {
      float mu  = p.st1[tid] * (1.0f / NN);
      float var = p.st1[64 + tid] * (1.0f / NN) - mu * mu;
      float s   = p.g1[tid] * rsqrtf(var + BN_EPS);
      sc[tid] = s;
      sh[tid] = p.be1[tid] - mu * s;
    }
    __syncthreads();
    const int NV = NN * 32;
    for (int i = gid; i < NV; i += gsz) {
      __half2 hv = ((const __half2*)p.h1h)[i];
      int c0 = (i * 2) & 63;
      float vx = fmaxf(fmaf(__half2float(hv.x), sc[c0],     sh[c0]),     0.f);
      float vy = fmaxf(fmaf(__half2float(hv.y), sc[c0 + 1], sh[c0 + 1]), 0.f);
      ((float2*)p.x2)[i] = make_float2(vx, vy);
    }
  }
  gbar(p.bar);

  // ================= P9: head (R13 body; tid<256; 500 virtual blocks) ======
  if (tid < 256) {
    int c = tid & 127, g = tid >> 7;
    float wsr[64], wtr[64];
#pragma unroll
    for (int k = 0; k < 64; ++k) {
      wsr[k] = p.wstT[k * 256 + c];
      wtr[k] = p.wstT[k * 256 + 128 + c];
    }
    float sb = p.s_b[c], tb = p.t_b[c];
    for (int vb = blk; vb < 500; vb += GRID) {
      int n0 = vb * 20 + g * 10;
      int n1 = n0 + 10; if (n1 > NN) n1 = NN;
      if (n0 >= NN) continue;
      int bcur = p.batch[n0];
      float facc = 0.f;
      for (int n = n0; n < n1; ++n) {
        const float4* xr = (const float4*)(p.x2 + (size_t)n * 64);
        float as = 0.f, at = 0.f;
#pragma unroll
        for (int q = 0; q < 16; ++q) {
          float4 xv = xr[q];
          as = fmaf(xv.x, wsr[4*q+0], as); at = fmaf(xv.x, wtr[4*q+0], at);
          as = fmaf(xv.y, wsr[4*q+1], as); at = fmaf(xv.y, wtr[4*q+1], at);
          as = fmaf(xv.z, wsr[4*q+2], as); at = fmaf(xv.z, wtr[4*q+2], at);
          as = fmaf(xv.w, wsr[4*q+3], as); at = fmaf(xv.w, wtr[4*q+3], at);
        }
        float sv = fminf(30.f, fmaxf(-30.f, as + sb));
        float tv = at + tb;
        float f  = tanhf(tv) / (1.f + expf(sv));
        int b = p.batch[n];
        if (b != bcur) {
          unsafeAtomicAdd(&p.out[bcur * 128 + c], facc);
          bcur = b; facc = 0.f;
        }
        facc += f;
      }
      unsafeAtomicAdd(&p.out[bcur * 128 + c], facc);
    }
  }
}

// ---------------------------------------------------------------------------
extern "C" void kernel_launch(void* const* d_in, const int* in_sizes, int n_in,
                              void* d_out, int out_size, void* d_ws, size_t ws_size,
                              hipStream_t stream)
{
  P prm;
  prm.x     = (const float*)d_in[0];
  prm.ei    = (const int*)d_in[1];
  prm.ea    = (const float*)d_in[2];
  prm.batch = (const int*)d_in[3];
  // d_in[4] edge_batch: unused by the reference
  prm.w0    = (const float*)d_in[5];
  prm.b0    = (const float*)d_in[6];
  prm.root0 = (const float*)d_in[7];
  prm.bias0 = (const float*)d_in[8];
  prm.g0    = (const float*)d_in[9];
  prm.be0   = (const float*)d_in[10];
  prm.w1    = (const float*)d_in[11];
  prm.b1    = (const float*)d_in[12];
  prm.root1 = (const float*)d_in[13];
  prm.bias1 = (const float*)d_in[14];
  prm.g1    = (const float*)d_in[15];
  prm.be1   = (const float*)d_in[16];
  prm.s_w   = (const float*)d_in[17];
  prm.s_b   = (const float*)d_in[18];
  prm.t_w   = (const float*)d_in[19];
  prm.t_b   = (const float*)d_in[20];
  prm.out   = (float*)d_out;

  float* ws = (float*)d_ws;
  prm.G0h = (unsigned short*)ws;  ws += 1440000;   // N*288 bf16
  prm.G1h = (unsigned short*)ws;  ws += 2880000;   // N*576 bf16
  prm.h0h = (__half*)ws;          ws += 160000;    // N*32 f16
  prm.h1h = (__half*)ws;          ws += 320000;    // N*64 f16
  prm.x1  = ws;                   ws += 320000;    // N*32 f32
  prm.x2  = ws;                   ws += 640000;    // N*64 f32
  prm.st0 = ws;                   ws += 64;
  prm.st1 = ws;                   ws += 128;
  prm.wstT= ws;                   ws += 16384;
  prm.wT0 = ws;                   ws += 5120;
  prm.wT1 = ws;                   ws += 20480;
  prm.ei2 = (int2*)ws;            ws += NE * 2;    // 8B-aligned (even offset)
  prm.bar = (unsigned int*)ws;    ws += 16;

  hipMemsetAsync((void*)prm.bar, 0, 64, stream);
  hipLaunchKernelGGL(mega, dim3(GRID), dim3(BLK), 0, stream, prm);
}

// Round 17
// 189.747 us; speedup vs baseline: 1.8622x; 1.8622x over previous
//
#include <hip/hip_runtime.h>
#include <hip/hip_fp16.h>
#include <math.h>

#define NN 10000
#define NE 100000
#define BN_EPS 1e-5f

// Lessons (measured):
//  R1: no f32 pk atomic on gfx950; f16/bf16 pk atomics DO exist.
//  R0: 212. R7: bf16 G = 203. R8: persistent edge waves = 203 (neutral).
//  R9: BN fused into hot GEMV loops = 225 REGRESSION (loop pollution).
//  R10: pk-f16 atomics + 2-col lanes = 191. R11: 4-col lanes = 203 REGR.
//  R12: +ei2/vec-ea = 192 (flat). R13: occupancy bundle = 187 (BEST).
//  R14: megakernel w/ spin barrier @GRID=256: correct but 353 total
//      (latency-bound at 5 waves/CU: VALUBusy 6.5%, HBM 5.3%).
//  R15 (GRID=768) and R16 (GRID=512, co-residency provable): both failed
//      with Trio-nursery errors (hang-or-infra, indistinguishable).
//      Pre-commit honored: megakernel line ABANDONED.
//  R17: revert to R13 verbatim (proven 187.3us) to re-establish baseline.

__device__ __forceinline__ unsigned short f2bf(float f) {
  unsigned int u = __float_as_uint(f);
  u += 0x7FFF + ((u >> 16) & 1);          // round-to-nearest-even
  return (unsigned short)(u >> 16);
}
__device__ __forceinline__ float bf2f(unsigned short h) {
  return __uint_as_float(((unsigned int)h) << 16);
}

// ---------------------------------------------------------------------------
// K0: prep. Pre-transpose weights; zero out/st; pack ei -> int2.
// ---------------------------------------------------------------------------
__global__ __launch_bounds__(256) void k_prep(
    const float* __restrict__ w0, const float* __restrict__ b0,
    const float* __restrict__ root0,
    const float* __restrict__ w1, const float* __restrict__ b1,
    const float* __restrict__ root1,
    const float* __restrict__ s_w, const float* __restrict__ t_w,
    const int* __restrict__ ei, int2* __restrict__ ei2,
    float* __restrict__ wT0, float* __restrict__ wT1, float* __restrict__ wstT,
    float* __restrict__ st0, float* __restrict__ st1, float* __restrict__ out)
{
  int gid = blockIdx.x * 256 + threadIdx.x;
  int gsz = gridDim.x * 256;
  for (int e = gid; e < NE; e += gsz)
    ei2[e] = make_int2(ei[e], ei[NE + e]);
  for (int idx = gid; idx < 16 * 320; idx += gsz) {
    int i = idx / 320, c = idx - i * 320;
    float v;
    if (c < 256)      v = w0[(i * 32 + (c & 31)) * 8 + (c >> 5)];
    else if (c < 288) v = b0[i * 32 + (c - 256)];
    else              v = root0[i * 32 + (c - 288)];
    wT0[idx] = v;
  }
  for (int idx = gid; idx < 32 * 640; idx += gsz) {
    int i = idx / 640, c = idx - i * 640;
    float v;
    if (c < 512)      v = w1[(i * 64 + (c & 63)) * 8 + (c >> 6)];
    else if (c < 576) v = b1[i * 64 + (c - 512)];
    else              v = root1[i * 64 + (c - 576)];
    wT1[idx] = v;
  }
  for (int idx = gid; idx < 64 * 256; idx += gsz) {
    int i = idx >> 8, o = idx & 255;
    wstT[idx] = (o < 128) ? s_w[o * 64 + i] : t_w[(o - 128) * 64 + i];
  }
  for (int idx = gid; idx < 64 * 128; idx += gsz) out[idx] = 0.f;
  if (gid < 64)  st0[gid] = 0.f;
  if (gid < 128) st1[gid] = 0.f;
}

// ---------------------------------------------------------------------------
// K1: layer-0 node GEMV; G0 bf16; node-term f16. 1000 blocks x 10 nodes.
// ---------------------------------------------------------------------------
__global__ __launch_bounds__(320) void k_node0(
    const float* __restrict__ x, const float* __restrict__ wT0,
    const float* __restrict__ bias0,
    unsigned short* __restrict__ G0h, __half* __restrict__ h0h)
{
  int c = threadIdx.x;
  float wc[16];
#pragma unroll
  for (int i = 0; i < 16; ++i) wc[i] = wT0[i * 320 + c];
  float bi = (c >= 288) ? bias0[c - 288] : 0.f;

  int n0 = blockIdx.x * 10;
  for (int n = n0; n < n0 + 10; n += 2) {
    const float4* xa = (const float4*)(x + n * 16);
    float a0 = 0.f, a1 = 0.f;
#pragma unroll
    for (int q = 0; q < 4; ++q) {
      float4 v0 = xa[q], v1 = xa[q + 4];
      a0 = fmaf(v0.x, wc[4 * q + 0], a0); a1 = fmaf(v1.x, wc[4 * q + 0], a1);
      a0 = fmaf(v0.y, wc[4 * q + 1], a0); a1 = fmaf(v1.y, wc[4 * q + 1], a1);
      a0 = fmaf(v0.z, wc[4 * q + 2], a0); a1 = fmaf(v1.z, wc[4 * q + 2], a1);
      a0 = fmaf(v0.w, wc[4 * q + 3], a0); a1 = fmaf(v1.w, wc[4 * q + 3], a1);
    }
    if (c < 288) {
      G0h[n * 288 + c]       = f2bf(a0);
      G0h[(n + 1) * 288 + c] = f2bf(a1);
    } else {
      h0h[n * 32 + (c - 288)]       = __float2half(a0 + bi);
      h0h[(n + 1) * 32 + (c - 288)] = __float2half(a1 + bi);
    }
  }
}

// ---------------------------------------------------------------------------
// K2: layer-0 edge kernel. 2-col lanes, pk-f16, persistent 2048 x 16 slots.
// ---------------------------------------------------------------------------
__global__ __launch_bounds__(256) void k_edge0(
    const int2* __restrict__ ei2, const float* __restrict__ ea,
    const unsigned short* __restrict__ G0h, __half* __restrict__ h0h)
{
  int tid = threadIdx.x;
  int slot = tid >> 4;              // 0..15
  int oo = (tid & 15) * 2;          // col pair base
  int stride = gridDim.x * 16;
  for (int e = blockIdx.x * 16 + slot; e < NE; e += stride) {
    int2 sd = ei2[e];
    const unsigned short* gr = G0h + sd.x * 288;
    const float4* ep = (const float4*)(ea + (size_t)e * 8);
    float4 e0 = ep[0], e1 = ep[1];
    float m0 = bf2f(gr[256 + oo]), m1 = bf2f(gr[256 + oo + 1]);
#pragma unroll
    for (int k = 0; k < 8; ++k) {
      ushort2 g2 = *(const ushort2*)(gr + k * 32 + oo);
      float ek = (k < 4) ? ((k == 0) ? e0.x : (k == 1) ? e0.y : (k == 2) ? e0.z : e0.w)
                         : ((k == 4) ? e1.x : (k == 5) ? e1.y : (k == 6) ? e1.z : e1.w);
      m0 = fmaf(ek, bf2f(g2.x), m0);
      m1 = fmaf(ek, bf2f(g2.y), m1);
    }
    unsafeAtomicAdd((__half2*)(h0h + sd.y * 32 + oo), __floats2half2_rn(m0, m1));
  }
}

// ---------------------------------------------------------------------------
// K3/K5: per-column sum & sumsq (BN stats) over f16 h. Grid 256.
// ---------------------------------------------------------------------------
template <int C>
__global__ __launch_bounds__(256) void k_stats(
    const __half* __restrict__ hh, float* __restrict__ st)
{
  const int RPB = 256 / C;
  int tid = threadIdx.x;
  int col = tid % C, rg = tid / C;
  float s1 = 0.f, s2 = 0.f;
  int step = gridDim.x * RPB;
  for (int n = blockIdx.x * RPB + rg; n < NN; n += step) {
    float v = __half2float(hh[n * C + col]);
    s1 += v; s2 += v * v;
  }
  __shared__ float l1[256], l2[256];
  l1[tid] = s1; l2[tid] = s2;
  __syncthreads();
  if (tid < C) {
    for (int r = 1; r < RPB; ++r) { s1 += l1[r * C + tid]; s2 += l2[r * C + tid]; }
    unsafeAtomicAdd(&st[tid], s1);
    unsafeAtomicAdd(&st[C + tid], s2);
  }
}

// ---------------------------------------------------------------------------
// K4a: x1 = relu(bn0(h0h)) -> f32. Grid 512.
// ---------------------------------------------------------------------------
__global__ __launch_bounds__(256) void k_x1(
    const __half* __restrict__ h0h, float* __restrict__ x1,
    const float* __restrict__ st0,
    const float* __restrict__ g0, const float* __restrict__ be0)
{
  __shared__ float sc[32], sh[32];
  int tid = threadIdx.x;
  if (tid < 32) {
    float mu  = st0[tid] * (1.0f / NN);
    float var = st0[32 + tid] * (1.0f / NN) - mu * mu;
    float s   = g0[tid] * rsqrtf(var + BN_EPS);
    sc[tid] = s;
    sh[tid] = be0[tid] - mu * s;
  }
  __syncthreads();
  const int NV = NN * 16;  // half2 count
  for (int i = blockIdx.x * 256 + tid; i < NV; i += gridDim.x * 256) {
    __half2 hv = ((const __half2*)h0h)[i];
    int c0 = (i * 2) & 31;
    float vx = fmaxf(fmaf(__half2float(hv.x), sc[c0],     sh[c0]),     0.f);
    float vy = fmaxf(fmaf(__half2float(hv.y), sc[c0 + 1], sh[c0 + 1]), 0.f);
    ((float2*)x1)[i] = make_float2(vx, vy);
  }
}

// ---------------------------------------------------------------------------
// K4b: layer-1 node GEMV; G1 bf16; node-term f16. 1000 blocks x 10.
// ---------------------------------------------------------------------------
__global__ __launch_bounds__(320) void k_node1(
    const float* __restrict__ x1, const float* __restrict__ wT1,
    const float* __restrict__ bias1,
    unsigned short* __restrict__ G1h, __half* __restrict__ h1h)
{
  int t = threadIdx.x;
  float wa[32], wb[32];
#pragma unroll
  for (int i = 0; i < 32; ++i) {
    float2 w2 = *(const float2*)(wT1 + i * 640 + 2 * t);
    wa[i] = w2.x; wb[i] = w2.y;
  }
  float bia = 0.f, bib = 0.f;
  if (t >= 288) { bia = bias1[2 * (t - 288)]; bib = bias1[2 * (t - 288) + 1]; }

  int n0 = blockIdx.x * 10;
  for (int n = n0; n < n0 + 10; n += 2) {
    const float4* xa = (const float4*)(x1 + n * 32);
    float a00 = 0.f, a01 = 0.f, a10 = 0.f, a11 = 0.f;
#pragma unroll
    for (int q = 0; q < 8; ++q) {
      float4 v0 = xa[q], v1 = xa[q + 8];
      a00 = fmaf(v0.x, wa[4 * q + 0], a00); a01 = fmaf(v0.x, wb[4 * q + 0], a01);
      a00 = fmaf(v0.y, wa[4 * q + 1], a00); a01 = fmaf(v0.y, wb[4 * q + 1], a01);
      a00 = fmaf(v0.z, wa[4 * q + 2], a00); a01 = fmaf(v0.z, wb[4 * q + 2], a01);
      a00 = fmaf(v0.w, wa[4 * q + 3], a00); a01 = fmaf(v0.w, wb[4 * q + 3], a01);
      a10 = fmaf(v1.x, wa[4 * q + 0], a10); a11 = fmaf(v1.x, wb[4 * q + 0], a11);
      a10 = fmaf(v1.y, wa[4 * q + 1], a10); a11 = fmaf(v1.y, wb[4 * q + 1], a11);
      a10 = fmaf(v1.z, wa[4 * q + 2], a10); a11 = fmaf(v1.z, wb[4 * q + 2], a11);
      a10 = fmaf(v1.w, wa[4 * q + 3], a10); a11 = fmaf(v1.w, wb[4 * q + 3], a11);
    }
    if (t < 288) {
      *(ushort2*)(G1h + n * 576 + 2 * t)       = make_ushort2(f2bf(a00), f2bf(a01));
      *(ushort2*)(G1h + (n + 1) * 576 + 2 * t) = make_ushort2(f2bf(a10), f2bf(a11));
    } else {
      int o = 2 * (t - 288);
      *(__half2*)(h1h + n * 64 + o)       = __floats2half2_rn(a00 + bia, a01 + bib);
      *(__half2*)(h1h + (n + 1) * 64 + o) = __floats2half2_rn(a10 + bia, a11 + bib);
    }
  }
}

// ---------------------------------------------------------------------------
// K6: layer-1 edge kernel. 2-col lanes, pk-f16, persistent 2048 x 8 slots.
// ---------------------------------------------------------------------------
__global__ __launch_bounds__(256) void k_edge1(
    const int2* __restrict__ ei2, const float* __restrict__ ea,
    const unsigned short* __restrict__ G1h, __half* __restrict__ h1h)
{
  int tid = threadIdx.x;
  int slot = tid >> 5;              // 0..7
  int oo = (tid & 31) * 2;          // col pair base
  int stride = gridDim.x * 8;
  for (int e = blockIdx.x * 8 + slot; e < NE; e += stride) {
    int2 sd = ei2[e];
    const unsigned short* gr = G1h + sd.x * 576;
    const float4* ep = (const float4*)(ea + (size_t)e * 8);
    float4 e0 = ep[0], e1 = ep[1];
    float m0 = bf2f(gr[512 + oo]), m1 = bf2f(gr[512 + oo + 1]);
#pragma unroll
    for (int k = 0; k < 8; ++k) {
      ushort2 g2 = *(const ushort2*)(gr + k * 64 + oo);
      float ek = (k < 4) ? ((k == 0) ? e0.x : (k == 1) ? e0.y : (k == 2) ? e0.z : e0.w)
                         : ((k == 4) ? e1.x : (k == 5) ? e1.y : (k == 6) ? e1.z : e1.w);
      m0 = fmaf(ek, bf2f(g2.x), m0);
      m1 = fmaf(ek, bf2f(g2.y), m1);
    }
    unsafeAtomicAdd((__half2*)(h1h + sd.y * 64 + oo), __floats2half2_rn(m0, m1));
  }
}

// ---------------------------------------------------------------------------
// K6b: x2 = relu(bn1(h1h)) -> f32. Grid 512.
// ---------------------------------------------------------------------------
__global__ __launch_bounds__(256) void k_x2(
    const __half* __restrict__ h1h, float* __restrict__ x2,
    const float* __restrict__ st1,
    const float* __restrict__ g1, const float* __restrict__ be1)
{
  __shared__ float sc[64], sh[64];
  int tid = threadIdx.x;
  if (tid < 64) {
    float mu  = st1[tid] * (1.0f / NN);
    float var = st1[64 + tid] * (1.0f / NN) - mu * mu;
    float s   = g1[tid] * rsqrtf(var + BN_EPS);
    sc[tid] = s;
    sh[tid] = be1[tid] - mu * s;
  }
  __syncthreads();
  const int NV = NN * 32;  // half2 count
  for (int i = blockIdx.x * 256 + tid; i < NV; i += gridDim.x * 256) {
    __half2 hv = ((const __half2*)h1h)[i];
    int c0 = (i * 2) & 63;
    float vx = fmaxf(fmaf(__half2float(hv.x), sc[c0],     sh[c0]),     0.f);
    float vy = fmaxf(fmaf(__half2float(hv.y), sc[c0 + 1], sh[c0 + 1]), 0.f);
    ((float2*)x2)[i] = make_float2(vx, vy);
  }
}

// ---------------------------------------------------------------------------
// K7: head reading f32 x2. 500 blocks x (2 groups x 10 nodes).
// ---------------------------------------------------------------------------
__global__ __launch_bounds__(256) void k_head(
    const float* __restrict__ x2, const float* __restrict__ wstT,
    const float* __restrict__ s_b, const float* __restrict__ t_b,
    const int* __restrict__ batch, float* __restrict__ out)
{
  int tid = threadIdx.x;
  int c = tid & 127, g = tid >> 7;
  int n0 = blockIdx.x * 20 + g * 10;
  int n1 = n0 + 10;
  if (n0 >= NN) return;
  if (n1 > NN) n1 = NN;

  float wsr[64], wtr[64];
#pragma unroll
  for (int k = 0; k < 64; ++k) {
    wsr[k] = wstT[k * 256 + c];
    wtr[k] = wstT[k * 256 + 128 + c];
  }
  float sb = s_b[c], tb = t_b[c];

  int bcur = batch[n0];
  float facc = 0.f;
  for (int n = n0; n < n1; ++n) {
    const float4* xr = (const float4*)(x2 + (size_t)n * 64);
    float as = 0.f, at = 0.f;
#pragma unroll
    for (int q = 0; q < 16; ++q) {
      float4 xv = xr[q];
      as = fmaf(xv.x, wsr[4 * q + 0], as); at = fmaf(xv.x, wtr[4 * q + 0], at);
      as = fmaf(xv.y, wsr[4 * q + 1], as); at = fmaf(xv.y, wtr[4 * q + 1], at);
      as = fmaf(xv.z, wsr[4 * q + 2], as); at = fmaf(xv.z, wtr[4 * q + 2], at);
      as = fmaf(xv.w, wsr[4 * q + 3], as); at = fmaf(xv.w, wtr[4 * q + 3], at);
    }
    float sv = fminf(30.f, fmaxf(-30.f, as + sb));
    float tv = at + tb;
    float f  = tanhf(tv) / (1.f + expf(sv));
    int b = batch[n];
    if (b != bcur) {
      unsafeAtomicAdd(&out[bcur * 128 + c], facc);
      bcur = b; facc = 0.f;
    }
    facc += f;
  }
  unsafeAtomicAdd(&out[bcur * 128 + c], facc);
}

// ---------------------------------------------------------------------------
extern "C" void kernel_launch(void* const* d_in, const int* in_sizes, int n_in,
                              void* d_out, int out_size, void* d_ws, size_t ws_size,
                              hipStream_t stream)
{
  const float* x     = (const float*)d_in[0];
  const int*   ei    = (const int*)d_in[1];
  const float* ea    = (const float*)d_in[2];
  const int*   batch = (const int*)d_in[3];
  // d_in[4] edge_batch: unused by the reference
  const float* w0    = (const float*)d_in[5];
  const float* b0    = (const float*)d_in[6];
  const float* root0 = (const float*)d_in[7];
  const float* bias0 = (const float*)d_in[8];
  const float* g0    = (const float*)d_in[9];
  const float* be0   = (const float*)d_in[10];
  const float* w1    = (const float*)d_in[11];
  const float* b1    = (const float*)d_in[12];
  const float* root1 = (const float*)d_in[13];
  const float* bias1 = (const float*)d_in[14];
  const float* g1    = (const float*)d_in[15];
  const float* be1   = (const float*)d_in[16];
  const float* s_w   = (const float*)d_in[17];
  const float* s_b   = (const float*)d_in[18];
  const float* t_w   = (const float*)d_in[19];
  const float* t_b   = (const float*)d_in[20];
  float* out = (float*)d_out;

  float* ws   = (float*)d_ws;
  unsigned short* G0h = (unsigned short*)ws;  ws += 1440000;  // N*288 bf16
  unsigned short* G1h = (unsigned short*)ws;  ws += 2880000;  // N*576 bf16
  __half* h0h = (__half*)ws;  ws += 160000;   // N*32 f16 accumulator
  __half* h1h = (__half*)ws;  ws += 320000;   // N*64 f16 accumulator
  float* x1   = ws;  ws += 320000;    // N*32 f32
  float* x2   = ws;  ws += 640000;    // N*64 f32
  float* st0  = ws;  ws += 64;
  float* st1  = ws;  ws += 128;
  float* wstT = ws;  ws += 16384;     // 64x256 transposed head weights
  float* wT0  = ws;  ws += 5120;      // 16x320
  float* wT1  = ws;  ws += 20480;     // 32x640
  int2* ei2   = (int2*)ws;            // NE packed (src,dst); 8B-aligned

  hipLaunchKernelGGL(k_prep, dim3(64), dim3(256), 0, stream,
                     w0, b0, root0, w1, b1, root1, s_w, t_w, ei, ei2,
                     wT0, wT1, wstT, st0, st1, out);
  hipLaunchKernelGGL(k_node0, dim3(1000), dim3(320), 0, stream,
                     x, wT0, bias0, G0h, h0h);
  hipLaunchKernelGGL(k_edge0, dim3(2048), dim3(256), 0, stream,
                     ei2, ea, G0h, h0h);
  hipLaunchKernelGGL(k_stats<32>, dim3(256), dim3(256), 0, stream, h0h, st0);
  hipLaunchKernelGGL(k_x1, dim3(512), dim3(256), 0, stream, h0h, x1, st0, g0, be0);
  hipLaunchKernelGGL(k_node1, dim3(1000), dim3(320), 0, stream,
                     x1, wT1, bias1, G1h, h1h);
  hipLaunchKernelGGL(k_edge1, dim3(2048), dim3(256), 0, stream,
                     ei2, ea, G1h, h1h);
  hipLaunchKernelGGL(k_stats<64>, dim3(256), dim3(256), 0, stream, h1h, st1);
  hipLaunchKernelGGL(k_x2, dim3(512), dim3(256), 0, stream, h1h, x2, st1, g1, be1);
  hipLaunchKernelGGL(k_head, dim3(500), dim3(256), 0, stream,
                     x2, wstT, s_b, t_b, batch, out);
}

// Round 18
// 173.570 us; speedup vs baseline: 2.0358x; 1.0932x over previous
//
#include <hip/hip_runtime.h>
#include <hip/hip_fp16.h>
#include <math.h>

#define NN 10000
#define NE 100000
#define BN_EPS 1e-5f

// Lessons (measured):
//  R0:212  R7 bf16-G:203  R10 pk-f16 atomics:191  R13 occupancy:187 (BEST)
//  R9: BN fused INSIDE hot GEMV loops = 225 REGRESSION (per-iter LDS reads).
//  R14: megakernel correct but latency-starved (353); R15/R16 hang-class
//      failures at higher grids => megakernel line abandoned (pre-commit).
//  R17: R13 verbatim reproduced at 189.7 => noise band +-3us, pod healthy.
//  R18: delete x1/x2 stages via BLOCK-LOCAL LDS PRE-PASS (not in-loop):
//      node1 block transforms its 10 rows into LDS once, then clean GEMV
//      reads LDS broadcast; head same for its 20 rows. 10 -> 8 dispatches.

__device__ __forceinline__ unsigned short f2bf(float f) {
  unsigned int u = __float_as_uint(f);
  u += 0x7FFF + ((u >> 16) & 1);          // round-to-nearest-even
  return (unsigned short)(u >> 16);
}
__device__ __forceinline__ float bf2f(unsigned short h) {
  return __uint_as_float(((unsigned int)h) << 16);
}

// ---------------------------------------------------------------------------
// K0: prep. Pre-transpose weights; zero out/st; pack ei -> int2. (unchanged)
// ---------------------------------------------------------------------------
__global__ __launch_bounds__(256) void k_prep(
    const float* __restrict__ w0, const float* __restrict__ b0,
    const float* __restrict__ root0,
    const float* __restrict__ w1, const float* __restrict__ b1,
    const float* __restrict__ root1,
    const float* __restrict__ s_w, const float* __restrict__ t_w,
    const int* __restrict__ ei, int2* __restrict__ ei2,
    float* __restrict__ wT0, float* __restrict__ wT1, float* __restrict__ wstT,
    float* __restrict__ st0, float* __restrict__ st1, float* __restrict__ out)
{
  int gid = blockIdx.x * 256 + threadIdx.x;
  int gsz = gridDim.x * 256;
  for (int e = gid; e < NE; e += gsz)
    ei2[e] = make_int2(ei[e], ei[NE + e]);
  for (int idx = gid; idx < 16 * 320; idx += gsz) {
    int i = idx / 320, c = idx - i * 320;
    float v;
    if (c < 256)      v = w0[(i * 32 + (c & 31)) * 8 + (c >> 5)];
    else if (c < 288) v = b0[i * 32 + (c - 256)];
    else              v = root0[i * 32 + (c - 288)];
    wT0[idx] = v;
  }
  for (int idx = gid; idx < 32 * 640; idx += gsz) {
    int i = idx / 640, c = idx - i * 640;
    float v;
    if (c < 512)      v = w1[(i * 64 + (c & 63)) * 8 + (c >> 6)];
    else if (c < 576) v = b1[i * 64 + (c - 512)];
    else              v = root1[i * 64 + (c - 576)];
    wT1[idx] = v;
  }
  for (int idx = gid; idx < 64 * 256; idx += gsz) {
    int i = idx >> 8, o = idx & 255;
    wstT[idx] = (o < 128) ? s_w[o * 64 + i] : t_w[(o - 128) * 64 + i];
  }
  for (int idx = gid; idx < 64 * 128; idx += gsz) out[idx] = 0.f;
  if (gid < 64)  st0[gid] = 0.f;
  if (gid < 128) st1[gid] = 0.f;
}

// ---------------------------------------------------------------------------
// K1: layer-0 node GEMV; G0 bf16; node-term f16. 1000 blocks x 10 nodes.
// (unchanged)
// ---------------------------------------------------------------------------
__global__ __launch_bounds__(320) void k_node0(
    const float* __restrict__ x, const float* __restrict__ wT0,
    const float* __restrict__ bias0,
    unsigned short* __restrict__ G0h, __half* __restrict__ h0h)
{
  int c = threadIdx.x;
  float wc[16];
#pragma unroll
  for (int i = 0; i < 16; ++i) wc[i] = wT0[i * 320 + c];
  float bi = (c >= 288) ? bias0[c - 288] : 0.f;

  int n0 = blockIdx.x * 10;
  for (int n = n0; n < n0 + 10; n += 2) {
    const float4* xa = (const float4*)(x + n * 16);
    float a0 = 0.f, a1 = 0.f;
#pragma unroll
    for (int q = 0; q < 4; ++q) {
      float4 v0 = xa[q], v1 = xa[q + 4];
      a0 = fmaf(v0.x, wc[4 * q + 0], a0); a1 = fmaf(v1.x, wc[4 * q + 0], a1);
      a0 = fmaf(v0.y, wc[4 * q + 1], a0); a1 = fmaf(v1.y, wc[4 * q + 1], a1);
      a0 = fmaf(v0.z, wc[4 * q + 2], a0); a1 = fmaf(v1.z, wc[4 * q + 2], a1);
      a0 = fmaf(v0.w, wc[4 * q + 3], a0); a1 = fmaf(v1.w, wc[4 * q + 3], a1);
    }
    if (c < 288) {
      G0h[n * 288 + c]       = f2bf(a0);
      G0h[(n + 1) * 288 + c] = f2bf(a1);
    } else {
      h0h[n * 32 + (c - 288)]       = __float2half(a0 + bi);
      h0h[(n + 1) * 32 + (c - 288)] = __float2half(a1 + bi);
    }
  }
}

// ---------------------------------------------------------------------------
// K2: layer-0 edge kernel. (unchanged: 2-col lanes, pk-f16, 2048x16 slots)
// ---------------------------------------------------------------------------
__global__ __launch_bounds__(256) void k_edge0(
    const int2* __restrict__ ei2, const float* __restrict__ ea,
    const unsigned short* __restrict__ G0h, __half* __restrict__ h0h)
{
  int tid = threadIdx.x;
  int slot = tid >> 4;              // 0..15
  int oo = (tid & 15) * 2;          // col pair base
  int stride = gridDim.x * 16;
  for (int e = blockIdx.x * 16 + slot; e < NE; e += stride) {
    int2 sd = ei2[e];
    const unsigned short* gr = G0h + sd.x * 288;
    const float4* ep = (const float4*)(ea + (size_t)e * 8);
    float4 e0 = ep[0], e1 = ep[1];
    float m0 = bf2f(gr[256 + oo]), m1 = bf2f(gr[256 + oo + 1]);
#pragma unroll
    for (int k = 0; k < 8; ++k) {
      ushort2 g2 = *(const ushort2*)(gr + k * 32 + oo);
      float ek = (k < 4) ? ((k == 0) ? e0.x : (k == 1) ? e0.y : (k == 2) ? e0.z : e0.w)
                         : ((k == 4) ? e1.x : (k == 5) ? e1.y : (k == 6) ? e1.z : e1.w);
      m0 = fmaf(ek, bf2f(g2.x), m0);
      m1 = fmaf(ek, bf2f(g2.y), m1);
    }
    unsafeAtomicAdd((__half2*)(h0h + sd.y * 32 + oo), __floats2half2_rn(m0, m1));
  }
}

// ---------------------------------------------------------------------------
// K3/K5: per-column sum & sumsq (BN stats) over f16 h. Grid 256. (unchanged)
// ---------------------------------------------------------------------------
template <int C>
__global__ __launch_bounds__(256) void k_stats(
    const __half* __restrict__ hh, float* __restrict__ st)
{
  const int RPB = 256 / C;
  int tid = threadIdx.x;
  int col = tid % C, rg = tid / C;
  float s1 = 0.f, s2 = 0.f;
  int step = gridDim.x * RPB;
  for (int n = blockIdx.x * RPB + rg; n < NN; n += step) {
    float v = __half2float(hh[n * C + col]);
    s1 += v; s2 += v * v;
  }
  __shared__ float l1[256], l2[256];
  l1[tid] = s1; l2[tid] = s2;
  __syncthreads();
  if (tid < C) {
    for (int r = 1; r < RPB; ++r) { s1 += l1[r * C + tid]; s2 += l2[r * C + tid]; }
    unsafeAtomicAdd(&st[tid], s1);
    unsafeAtomicAdd(&st[C + tid], s2);
  }
}

// ---------------------------------------------------------------------------
// K4: layer-1 node GEMV with LDS PRE-PASS x1 (x1 never hits global).
// Prologue: 320 threads = 10 nodes x 32 cols, one BN+relu element each into
// xs[]; barrier; then the UNCHANGED register-pure GEMV reads xs broadcast.
// ---------------------------------------------------------------------------
__global__ __launch_bounds__(320) void k_node1(
    const __half* __restrict__ h0h, const float* __restrict__ st0,
    const float* __restrict__ g0, const float* __restrict__ be0,
    const float* __restrict__ wT1, const float* __restrict__ bias1,
    unsigned short* __restrict__ G1h, __half* __restrict__ h1h)
{
  __shared__ float sc[32], sh[32];
  __shared__ float xs[320];           // 10 nodes x 32 cols
  int t = threadIdx.x;
  int n0 = blockIdx.x * 10;

  if (t < 32) {
    float mu  = st0[t] * (1.0f / NN);
    float var = st0[32 + t] * (1.0f / NN) - mu * mu;
    float s   = g0[t] * rsqrtf(var + BN_EPS);
    sc[t] = s;
    sh[t] = be0[t] - mu * s;
  }

  float wa[32], wb[32];
#pragma unroll
  for (int i = 0; i < 32; ++i) {
    float2 w2 = *(const float2*)(wT1 + i * 640 + 2 * t);
    wa[i] = w2.x; wb[i] = w2.y;
  }
  float bia = 0.f, bib = 0.f;
  if (t >= 288) { bia = bias1[2 * (t - 288)]; bib = bias1[2 * (t - 288) + 1]; }

  __syncthreads();                    // sc/sh ready
  {
    int col = t & 31;
    float hv = __half2float(h0h[(n0 + (t >> 5)) * 32 + col]);
    xs[t] = fmaxf(fmaf(hv, sc[col], sh[col]), 0.f);
  }
  __syncthreads();                    // xs ready

  for (int n = n0; n < n0 + 10; n += 2) {
    const float4* xa = (const float4*)(xs + (n - n0) * 32);
    float a00 = 0.f, a01 = 0.f, a10 = 0.f, a11 = 0.f;
#pragma unroll
    for (int q = 0; q < 8; ++q) {
      float4 v0 = xa[q], v1 = xa[q + 8];
      a00 = fmaf(v0.x, wa[4 * q + 0], a00); a01 = fmaf(v0.x, wb[4 * q + 0], a01);
      a00 = fmaf(v0.y, wa[4 * q + 1], a00); a01 = fmaf(v0.y, wb[4 * q + 1], a01);
      a00 = fmaf(v0.z, wa[4 * q + 2], a00); a01 = fmaf(v0.z, wb[4 * q + 2], a01);
      a00 = fmaf(v0.w, wa[4 * q + 3], a00); a01 = fmaf(v0.w, wb[4 * q + 3], a01);
      a10 = fmaf(v1.x, wa[4 * q + 0], a10); a11 = fmaf(v1.x, wb[4 * q + 0], a11);
      a10 = fmaf(v1.y, wa[4 * q + 1], a10); a11 = fmaf(v1.y, wb[4 * q + 1], a11);
      a10 = fmaf(v1.z, wa[4 * q + 2], a10); a11 = fmaf(v1.z, wb[4 * q + 2], a11);
      a10 = fmaf(v1.w, wa[4 * q + 3], a10); a11 = fmaf(v1.w, wb[4 * q + 3], a11);
    }
    if (t < 288) {
      *(ushort2*)(G1h + n * 576 + 2 * t)       = make_ushort2(f2bf(a00), f2bf(a01));
      *(ushort2*)(G1h + (n + 1) * 576 + 2 * t) = make_ushort2(f2bf(a10), f2bf(a11));
    } else {
      int o = 2 * (t - 288);
      *(__half2*)(h1h + n * 64 + o)       = __floats2half2_rn(a00 + bia, a01 + bib);
      *(__half2*)(h1h + (n + 1) * 64 + o) = __floats2half2_rn(a10 + bia, a11 + bib);
    }
  }
}

// ---------------------------------------------------------------------------
// K6: layer-1 edge kernel. (unchanged: 2-col lanes, pk-f16, 2048x8 slots)
// ---------------------------------------------------------------------------
__global__ __launch_bounds__(256) void k_edge1(
    const int2* __restrict__ ei2, const float* __restrict__ ea,
    const unsigned short* __restrict__ G1h, __half* __restrict__ h1h)
{
  int tid = threadIdx.x;
  int slot = tid >> 5;              // 0..7
  int oo = (tid & 31) * 2;          // col pair base
  int stride = gridDim.x * 8;
  for (int e = blockIdx.x * 8 + slot; e < NE; e += stride) {
    int2 sd = ei2[e];
    const unsigned short* gr = G1h + sd.x * 576;
    const float4* ep = (const float4*)(ea + (size_t)e * 8);
    float4 e0 = ep[0], e1 = ep[1];
    float m0 = bf2f(gr[512 + oo]), m1 = bf2f(gr[512 + oo + 1]);
#pragma unroll
    for (int k = 0; k < 8; ++k) {
      ushort2 g2 = *(const ushort2*)(gr + k * 64 + oo);
      float ek = (k < 4) ? ((k == 0) ? e0.x : (k == 1) ? e0.y : (k == 2) ? e0.z : e0.w)
                         : ((k == 4) ? e1.x : (k == 5) ? e1.y : (k == 6) ? e1.z : e1.w);
      m0 = fmaf(ek, bf2f(g2.x), m0);
      m1 = fmaf(ek, bf2f(g2.y), m1);
    }
    unsafeAtomicAdd((__half2*)(h1h + sd.y * 64 + oo), __floats2half2_rn(m0, m1));
  }
}

// ---------------------------------------------------------------------------
// K7: head with LDS PRE-PASS x2 (x2 never hits global).
// Prologue: 1280 elements (20 nodes x 64 cols) over 256 threads into xs[];
// barrier; UNCHANGED register-column head loop reads xs broadcast.
// Grid: 500 blocks x (2 groups x 10 nodes).
// ---------------------------------------------------------------------------
__global__ __launch_bounds__(256) void k_head(
    const __half* __restrict__ h1h, const float* __restrict__ st1,
    const float* __restrict__ g1, const float* __restrict__ be1,
    const float* __restrict__ wstT,
    const float* __restrict__ s_b, const float* __restrict__ t_b,
    const int* __restrict__ batch, float* __restrict__ out)
{
  __shared__ float sc[64], sh[64];
  __shared__ float xs[1280];          // 20 nodes x 64 cols
  int tid = threadIdx.x;
  int nb = blockIdx.x * 20;           // block's first node

  if (tid < 64) {
    float mu  = st1[tid] * (1.0f / NN);
    float var = st1[64 + tid] * (1.0f / NN) - mu * mu;
    float s   = g1[tid] * rsqrtf(var + BN_EPS);
    sc[tid] = s;
    sh[tid] = be1[tid] - mu * s;
  }

  int c = tid & 127, g = tid >> 7;
  float wsr[64], wtr[64];
#pragma unroll
  for (int k = 0; k < 64; ++k) {
    wsr[k] = wstT[k * 256 + c];
    wtr[k] = wstT[k * 256 + 128 + c];
  }
  float sb = s_b[c], tb = t_b[c];

  __syncthreads();                    // sc/sh ready
#pragma unroll
  for (int r = 0; r < 5; ++r) {
    int i = tid + r * 256;            // 0..1279
    int col = i & 63;
    float hv = __half2float(h1h[(size_t)(nb + (i >> 6)) * 64 + col]);
    xs[i] = fmaxf(fmaf(hv, sc[col], sh[col]), 0.f);
  }
  __syncthreads();                    // xs ready

  int n0 = nb + g * 10;
  int n1 = n0 + 10;
  int bcur = batch[n0];
  float facc = 0.f;
  for (int n = n0; n < n1; ++n) {
    const float4* xr = (const float4*)(xs + (n - nb) * 64);
    float as = 0.f, at = 0.f;
#pragma unroll
    for (int q = 0; q < 16; ++q) {
      float4 xv = xr[q];
      as = fmaf(xv.x, wsr[4 * q + 0], as); at = fmaf(xv.x, wtr[4 * q + 0], at);
      as = fmaf(xv.y, wsr[4 * q + 1], as); at = fmaf(xv.y, wtr[4 * q + 1], at);
      as = fmaf(xv.z, wsr[4 * q + 2], as); at = fmaf(xv.z, wtr[4 * q + 2], at);
      as = fmaf(xv.w, wsr[4 * q + 3], as); at = fmaf(xv.w, wtr[4 * q + 3], at);
    }
    float sv = fminf(30.f, fmaxf(-30.f, as + sb));
    float tv = at + tb;
    float f  = tanhf(tv) / (1.f + expf(sv));
    int b = batch[n];
    if (b != bcur) {
      unsafeAtomicAdd(&out[bcur * 128 + c], facc);
      bcur = b; facc = 0.f;
    }
    facc += f;
  }
  unsafeAtomicAdd(&out[bcur * 128 + c], facc);
}

// ---------------------------------------------------------------------------
extern "C" void kernel_launch(void* const* d_in, const int* in_sizes, int n_in,
                              void* d_out, int out_size, void* d_ws, size_t ws_size,
                              hipStream_t stream)
{
  const float* x     = (const float*)d_in[0];
  const int*   ei    = (const int*)d_in[1];
  const float* ea    = (const float*)d_in[2];
  const int*   batch = (const int*)d_in[3];
  // d_in[4] edge_batch: unused by the reference
  const float* w0    = (const float*)d_in[5];
  const float* b0    = (const float*)d_in[6];
  const float* root0 = (const float*)d_in[7];
  const float* bias0 = (const float*)d_in[8];
  const float* g0    = (const float*)d_in[9];
  const float* be0   = (const float*)d_in[10];
  const float* w1    = (const float*)d_in[11];
  const float* b1    = (const float*)d_in[12];
  const float* root1 = (const float*)d_in[13];
  const float* bias1 = (const float*)d_in[14];
  const float* g1    = (const float*)d_in[15];
  const float* be1   = (const float*)d_in[16];
  const float* s_w   = (const float*)d_in[17];
  const float* s_b   = (const float*)d_in[18];
  const float* t_w   = (const float*)d_in[19];
  const float* t_b   = (const float*)d_in[20];
  float* out = (float*)d_out;

  float* ws   = (float*)d_ws;
  unsigned short* G0h = (unsigned short*)ws;  ws += 1440000;  // N*288 bf16
  unsigned short* G1h = (unsigned short*)ws;  ws += 2880000;  // N*576 bf16
  __half* h0h = (__half*)ws;  ws += 160000;   // N*32 f16 accumulator
  __half* h1h = (__half*)ws;  ws += 320000;   // N*64 f16 accumulator
  float* st0  = ws;  ws += 64;
  float* st1  = ws;  ws += 128;
  float* wstT = ws;  ws += 16384;     // 64x256 transposed head weights
  float* wT0  = ws;  ws += 5120;      // 16x320
  float* wT1  = ws;  ws += 20480;     // 32x640
  int2* ei2   = (int2*)ws;            // NE packed (src,dst); 8B-aligned

  hipLaunchKernelGGL(k_prep, dim3(64), dim3(256), 0, stream,
                     w0, b0, root0, w1, b1, root1, s_w, t_w, ei, ei2,
                     wT0, wT1, wstT, st0, st1, out);
  hipLaunchKernelGGL(k_node0, dim3(1000), dim3(320), 0, stream,
                     x, wT0, bias0, G0h, h0h);
  hipLaunchKernelGGL(k_edge0, dim3(2048), dim3(256), 0, stream,
                     ei2, ea, G0h, h0h);
  hipLaunchKernelGGL(k_stats<32>, dim3(256), dim3(256), 0, stream, h0h, st0);
  hipLaunchKernelGGL(k_node1, dim3(1000), dim3(320), 0, stream,
                     h0h, st0, g0, be0, wT1, bias1, G1h, h1h);
  hipLaunchKernelGGL(k_edge1, dim3(2048), dim3(256), 0, stream,
                     ei2, ea, G1h, h1h);
  hipLaunchKernelGGL(k_stats<64>, dim3(256), dim3(256), 0, stream, h1h, st1);
  hipLaunchKernelGGL(k_head, dim3(500), dim3(256), 0, stream,
                     h1h, st1, g1, be1, wstT, s_b, t_b, batch, out);
}

// Round 19
// 173.331 us; speedup vs baseline: 2.0386x; 1.0014x over previous
//
#include <hip/hip_runtime.h>
#include <hip/hip_fp16.h>
#include <math.h>

#define NN 10000
#define NE 100000
#define BN_EPS 1e-5f

// Lessons (measured):
//  R0:212  R7 bf16-G:203  R10 pk-f16:191  R13 occupancy:187  R18 LDS-prepass
//  fusion (10->8 stages): 173.6 (BEST). Stage overhead ~8us each confirmed.
//  R9 vs R18: BN fusion must be a block-local PRE-PASS, never in-loop.
//  R12: raw 2-load ei reads == packed ei2 (broadcast-absorbed) => ei2 free
//  to drop. R19: delete prep (8->7 stages): node0 stages w0/b0/root0 in LDS
//  per-block; wT1/wstT/zero jobs become grid-stride side-loops in node0
//  (stream order covers node1/head/stats consumers).

__device__ __forceinline__ unsigned short f2bf(float f) {
  unsigned int u = __float_as_uint(f);
  u += 0x7FFF + ((u >> 16) & 1);          // round-to-nearest-even
  return (unsigned short)(u >> 16);
}
__device__ __forceinline__ float bf2f(unsigned short h) {
  return __uint_as_float(((unsigned int)h) << 16);
}

// ---------------------------------------------------------------------------
// K1: layer-0 node GEMV + absorbed prep. 1000 blocks x 10 nodes.
//  Side jobs (grid-stride): wT1/wstT transposes, out/st zeroing.
//  Own weights: w0/b0/root0 staged in LDS (20KB), prologue-only reads.
//  GEMV body byte-identical to R18.
// ---------------------------------------------------------------------------
__global__ __launch_bounds__(320) void k_node0(
    const float* __restrict__ x,
    const float* __restrict__ w0, const float* __restrict__ b0,
    const float* __restrict__ root0, const float* __restrict__ bias0,
    const float* __restrict__ w1, const float* __restrict__ b1,
    const float* __restrict__ root1,
    const float* __restrict__ s_w, const float* __restrict__ t_w,
    unsigned short* __restrict__ G0h, __half* __restrict__ h0h,
    float* __restrict__ wT1, float* __restrict__ wstT,
    float* __restrict__ st0, float* __restrict__ st1, float* __restrict__ out)
{
  int t = threadIdx.x;
  int gid = blockIdx.x * 320 + t;
  int gsz = gridDim.x * 320;

  // --- side jobs for downstream kernels (stream order covers consumers) ---
  for (int idx = gid; idx < 32 * 640; idx += gsz) {
    int i = idx / 640, c = idx - i * 640;
    float v;
    if (c < 512)      v = w1[(i * 64 + (c & 63)) * 8 + (c >> 6)];
    else if (c < 576) v = b1[i * 64 + (c - 512)];
    else              v = root1[i * 64 + (c - 576)];
    wT1[idx] = v;
  }
  for (int idx = gid; idx < 64 * 256; idx += gsz) {
    int i = idx >> 8, o = idx & 255;
    wstT[idx] = (o < 128) ? s_w[o * 64 + i] : t_w[(o - 128) * 64 + i];
  }
  for (int idx = gid; idx < 64 * 128; idx += gsz) out[idx] = 0.f;
  if (gid < 64)  st0[gid] = 0.f;
  if (gid < 128) st1[gid] = 0.f;

  // --- stage own weights in LDS (coalesced global -> LDS) ---
  __shared__ float ws0[4096];           // w0: 512x8 = 16KB
  __shared__ float sb0[512], sr0[512];  // b0, root0: 2KB each
  for (int i = t; i < 4096; i += 320) ws0[i] = w0[i];
  for (int i = t; i < 512; i += 320) { sb0[i] = b0[i]; sr0[i] = root0[i]; }
  __syncthreads();

  int c = t;
  float wc[16];
  float bi = 0.f;
  if (c < 256) {
#pragma unroll
    for (int i = 0; i < 16; ++i) wc[i] = ws0[(i * 32 + (c & 31)) * 8 + (c >> 5)];
  } else if (c < 288) {
#pragma unroll
    for (int i = 0; i < 16; ++i) wc[i] = sb0[i * 32 + (c - 256)];
  } else {
#pragma unroll
    for (int i = 0; i < 16; ++i) wc[i] = sr0[i * 32 + (c - 288)];
    bi = bias0[c - 288];
  }

  int n0 = blockIdx.x * 10;
  for (int n = n0; n < n0 + 10; n += 2) {
    const float4* xa = (const float4*)(x + n * 16);
    float a0 = 0.f, a1 = 0.f;
#pragma unroll
    for (int q = 0; q < 4; ++q) {
      float4 v0 = xa[q], v1 = xa[q + 4];
      a0 = fmaf(v0.x, wc[4 * q + 0], a0); a1 = fmaf(v1.x, wc[4 * q + 0], a1);
      a0 = fmaf(v0.y, wc[4 * q + 1], a0); a1 = fmaf(v1.y, wc[4 * q + 1], a1);
      a0 = fmaf(v0.z, wc[4 * q + 2], a0); a1 = fmaf(v1.z, wc[4 * q + 2], a1);
      a0 = fmaf(v0.w, wc[4 * q + 3], a0); a1 = fmaf(v1.w, wc[4 * q + 3], a1);
    }
    if (c < 288) {
      G0h[n * 288 + c]       = f2bf(a0);
      G0h[(n + 1) * 288 + c] = f2bf(a1);
    } else {
      h0h[n * 32 + (c - 288)]       = __float2half(a0 + bi);
      h0h[(n + 1) * 32 + (c - 288)] = __float2half(a1 + bi);
    }
  }
}

// ---------------------------------------------------------------------------
// K2: layer-0 edge kernel. Raw ei reads (R12: neutral). Body unchanged.
// ---------------------------------------------------------------------------
__global__ __launch_bounds__(256) void k_edge0(
    const int* __restrict__ ei, const float* __restrict__ ea,
    const unsigned short* __restrict__ G0h, __half* __restrict__ h0h)
{
  int tid = threadIdx.x;
  int slot = tid >> 4;              // 0..15
  int oo = (tid & 15) * 2;          // col pair base
  int stride = gridDim.x * 16;
  for (int e = blockIdx.x * 16 + slot; e < NE; e += stride) {
    int src = ei[e], dst = ei[NE + e];
    const unsigned short* gr = G0h + src * 288;
    const float4* ep = (const float4*)(ea + (size_t)e * 8);
    float4 e0 = ep[0], e1 = ep[1];
    float m0 = bf2f(gr[256 + oo]), m1 = bf2f(gr[256 + oo + 1]);
#pragma unroll
    for (int k = 0; k < 8; ++k) {
      ushort2 g2 = *(const ushort2*)(gr + k * 32 + oo);
      float ek = (k < 4) ? ((k == 0) ? e0.x : (k == 1) ? e0.y : (k == 2) ? e0.z : e0.w)
                         : ((k == 4) ? e1.x : (k == 5) ? e1.y : (k == 6) ? e1.z : e1.w);
      m0 = fmaf(ek, bf2f(g2.x), m0);
      m1 = fmaf(ek, bf2f(g2.y), m1);
    }
    unsafeAtomicAdd((__half2*)(h0h + dst * 32 + oo), __floats2half2_rn(m0, m1));
  }
}

// ---------------------------------------------------------------------------
// K3/K5: per-column sum & sumsq (BN stats) over f16 h. Grid 256. (unchanged)
// ---------------------------------------------------------------------------
template <int C>
__global__ __launch_bounds__(256) void k_stats(
    const __half* __restrict__ hh, float* __restrict__ st)
{
  const int RPB = 256 / C;
  int tid = threadIdx.x;
  int col = tid % C, rg = tid / C;
  float s1 = 0.f, s2 = 0.f;
  int step = gridDim.x * RPB;
  for (int n = blockIdx.x * RPB + rg; n < NN; n += step) {
    float v = __half2float(hh[n * C + col]);
    s1 += v; s2 += v * v;
  }
  __shared__ float l1[256], l2[256];
  l1[tid] = s1; l2[tid] = s2;
  __syncthreads();
  if (tid < C) {
    for (int r = 1; r < RPB; ++r) { s1 += l1[r * C + tid]; s2 += l2[r * C + tid]; }
    unsafeAtomicAdd(&st[tid], s1);
    unsafeAtomicAdd(&st[C + tid], s2);
  }
}

// ---------------------------------------------------------------------------
// K4: layer-1 node GEMV with LDS PRE-PASS x1. (unchanged from R18)
// ---------------------------------------------------------------------------
__global__ __launch_bounds__(320) void k_node1(
    const __half* __restrict__ h0h, const float* __restrict__ st0,
    const float* __restrict__ g0, const float* __restrict__ be0,
    const float* __restrict__ wT1, const float* __restrict__ bias1,
    unsigned short* __restrict__ G1h, __half* __restrict__ h1h)
{
  __shared__ float sc[32], sh[32];
  __shared__ float xs[320];           // 10 nodes x 32 cols
  int t = threadIdx.x;
  int n0 = blockIdx.x * 10;

  if (t < 32) {
    float mu  = st0[t] * (1.0f / NN);
    float var = st0[32 + t] * (1.0f / NN) - mu * mu;
    float s   = g0[t] * rsqrtf(var + BN_EPS);
    sc[t] = s;
    sh[t] = be0[t] - mu * s;
  }

  float wa[32], wb[32];
#pragma unroll
  for (int i = 0; i < 32; ++i) {
    float2 w2 = *(const float2*)(wT1 + i * 640 + 2 * t);
    wa[i] = w2.x; wb[i] = w2.y;
  }
  float bia = 0.f, bib = 0.f;
  if (t >= 288) { bia = bias1[2 * (t - 288)]; bib = bias1[2 * (t - 288) + 1]; }

  __syncthreads();                    // sc/sh ready
  {
    int col = t & 31;
    float hv = __half2float(h0h[(n0 + (t >> 5)) * 32 + col]);
    xs[t] = fmaxf(fmaf(hv, sc[col], sh[col]), 0.f);
  }
  __syncthreads();                    // xs ready

  for (int n = n0; n < n0 + 10; n += 2) {
    const float4* xa = (const float4*)(xs + (n - n0) * 32);
    float a00 = 0.f, a01 = 0.f, a10 = 0.f, a11 = 0.f;
#pragma unroll
    for (int q = 0; q < 8; ++q) {
      float4 v0 = xa[q], v1 = xa[q + 8];
      a00 = fmaf(v0.x, wa[4 * q + 0], a00); a01 = fmaf(v0.x, wb[4 * q + 0], a01);
      a00 = fmaf(v0.y, wa[4 * q + 1], a00); a01 = fmaf(v0.y, wb[4 * q + 1], a01);
      a00 = fmaf(v0.z, wa[4 * q + 2], a00); a01 = fmaf(v0.z, wb[4 * q + 2], a01);
      a00 = fmaf(v0.w, wa[4 * q + 3], a00); a01 = fmaf(v0.w, wb[4 * q + 3], a01);
      a10 = fmaf(v1.x, wa[4 * q + 0], a10); a11 = fmaf(v1.x, wb[4 * q + 0], a11);
      a10 = fmaf(v1.y, wa[4 * q + 1], a10); a11 = fmaf(v1.y, wb[4 * q + 1], a11);
      a10 = fmaf(v1.z, wa[4 * q + 2], a10); a11 = fmaf(v1.z, wb[4 * q + 2], a11);
      a10 = fmaf(v1.w, wa[4 * q + 3], a10); a11 = fmaf(v1.w, wb[4 * q + 3], a11);
    }
    if (t < 288) {
      *(ushort2*)(G1h + n * 576 + 2 * t)       = make_ushort2(f2bf(a00), f2bf(a01));
      *(ushort2*)(G1h + (n + 1) * 576 + 2 * t) = make_ushort2(f2bf(a10), f2bf(a11));
    } else {
      int o = 2 * (t - 288);
      *(__half2*)(h1h + n * 64 + o)       = __floats2half2_rn(a00 + bia, a01 + bib);
      *(__half2*)(h1h + (n + 1) * 64 + o) = __floats2half2_rn(a10 + bia, a11 + bib);
    }
  }
}

// ---------------------------------------------------------------------------
// K6: layer-1 edge kernel. Raw ei reads. Body unchanged.
// ---------------------------------------------------------------------------
__global__ __launch_bounds__(256) void k_edge1(
    const int* __restrict__ ei, const float* __restrict__ ea,
    const unsigned short* __restrict__ G1h, __half* __restrict__ h1h)
{
  int tid = threadIdx.x;
  int slot = tid >> 5;              // 0..7
  int oo = (tid & 31) * 2;          // col pair base
  int stride = gridDim.x * 8;
  for (int e = blockIdx.x * 8 + slot; e < NE; e += stride) {
    int src = ei[e], dst = ei[NE + e];
    const unsigned short* gr = G1h + src * 576;
    const float4* ep = (const float4*)(ea + (size_t)e * 8);
    float4 e0 = ep[0], e1 = ep[1];
    float m0 = bf2f(gr[512 + oo]), m1 = bf2f(gr[512 + oo + 1]);
#pragma unroll
    for (int k = 0; k < 8; ++k) {
      ushort2 g2 = *(const ushort2*)(gr + k * 64 + oo);
      float ek = (k < 4) ? ((k == 0) ? e0.x : (k == 1) ? e0.y : (k == 2) ? e0.z : e0.w)
                         : ((k == 4) ? e1.x : (k == 5) ? e1.y : (k == 6) ? e1.z : e1.w);
      m0 = fmaf(ek, bf2f(g2.x), m0);
      m1 = fmaf(ek, bf2f(g2.y), m1);
    }
    unsafeAtomicAdd((__half2*)(h1h + dst * 64 + oo), __floats2half2_rn(m0, m1));
  }
}

// ---------------------------------------------------------------------------
// K7: head with LDS PRE-PASS x2. (unchanged from R18)
// ---------------------------------------------------------------------------
__global__ __launch_bounds__(256) void k_head(
    const __half* __restrict__ h1h, const float* __restrict__ st1,
    const float* __restrict__ g1, const float* __restrict__ be1,
    const float* __restrict__ wstT,
    const float* __restrict__ s_b, const float* __restrict__ t_b,
    const int* __restrict__ batch, float* __restrict__ out)
{
  __shared__ float sc[64], sh[64];
  __shared__ float xs[1280];          // 20 nodes x 64 cols
  int tid = threadIdx.x;
  int nb = blockIdx.x * 20;           // block's first node

  if (tid < 64) {
    float mu  = st1[tid] * (1.0f / NN);
    float var = st1[64 + tid] * (1.0f / NN) - mu * mu;
    float s   = g1[tid] * rsqrtf(var + BN_EPS);
    sc[tid] = s;
    sh[tid] = be1[tid] - mu * s;
  }

  int c = tid & 127, g = tid >> 7;
  float wsr[64], wtr[64];
#pragma unroll
  for (int k = 0; k < 64; ++k) {
    wsr[k] = wstT[k * 256 + c];
    wtr[k] = wstT[k * 256 + 128 + c];
  }
  float sb = s_b[c], tb = t_b[c];

  __syncthreads();                    // sc/sh ready
#pragma unroll
  for (int r = 0; r < 5; ++r) {
    int i = tid + r * 256;            // 0..1279
    int col = i & 63;
    float hv = __half2float(h1h[(size_t)(nb + (i >> 6)) * 64 + col]);
    xs[i] = fmaxf(fmaf(hv, sc[col], sh[col]), 0.f);
  }
  __syncthreads();                    // xs ready

  int n0 = nb + g * 10;
  int n1 = n0 + 10;
  int bcur = batch[n0];
  float facc = 0.f;
  for (int n = n0; n < n1; ++n) {
    const float4* xr = (const float4*)(xs + (n - nb) * 64);
    float as = 0.f, at = 0.f;
#pragma unroll
    for (int q = 0; q < 16; ++q) {
      float4 xv = xr[q];
      as = fmaf(xv.x, wsr[4 * q + 0], as); at = fmaf(xv.x, wtr[4 * q + 0], at);
      as = fmaf(xv.y, wsr[4 * q + 1], as); at = fmaf(xv.y, wtr[4 * q + 1], at);
      as = fmaf(xv.z, wsr[4 * q + 2], as); at = fmaf(xv.z, wtr[4 * q + 2], at);
      as = fmaf(xv.w, wsr[4 * q + 3], as); at = fmaf(xv.w, wtr[4 * q + 3], at);
    }
    float sv = fminf(30.f, fmaxf(-30.f, as + sb));
    float tv = at + tb;
    float f  = tanhf(tv) / (1.f + expf(sv));
    int b = batch[n];
    if (b != bcur) {
      unsafeAtomicAdd(&out[bcur * 128 + c], facc);
      bcur = b; facc = 0.f;
    }
    facc += f;
  }
  unsafeAtomicAdd(&out[bcur * 128 + c], facc);
}

// ---------------------------------------------------------------------------
extern "C" void kernel_launch(void* const* d_in, const int* in_sizes, int n_in,
                              void* d_out, int out_size, void* d_ws, size_t ws_size,
                              hipStream_t stream)
{
  const float* x     = (const float*)d_in[0];
  const int*   ei    = (const int*)d_in[1];
  const float* ea    = (const float*)d_in[2];
  const int*   batch = (const int*)d_in[3];
  // d_in[4] edge_batch: unused by the reference
  const float* w0    = (const float*)d_in[5];
  const float* b0    = (const float*)d_in[6];
  const float* root0 = (const float*)d_in[7];
  const float* bias0 = (const float*)d_in[8];
  const float* g0    = (const float*)d_in[9];
  const float* be0   = (const float*)d_in[10];
  const float* w1    = (const float*)d_in[11];
  const float* b1    = (const float*)d_in[12];
  const float* root1 = (const float*)d_in[13];
  const float* bias1 = (const float*)d_in[14];
  const float* g1    = (const float*)d_in[15];
  const float* be1   = (const float*)d_in[16];
  const float* s_w   = (const float*)d_in[17];
  const float* s_b   = (const float*)d_in[18];
  const float* t_w   = (const float*)d_in[19];
  const float* t_b   = (const float*)d_in[20];
  float* out = (float*)d_out;

  float* ws   = (float*)d_ws;
  unsigned short* G0h = (unsigned short*)ws;  ws += 1440000;  // N*288 bf16
  unsigned short* G1h = (unsigned short*)ws;  ws += 2880000;  // N*576 bf16
  __half* h0h = (__half*)ws;  ws += 160000;   // N*32 f16 accumulator
  __half* h1h = (__half*)ws;  ws += 320000;   // N*64 f16 accumulator
  float* st0  = ws;  ws += 64;
  float* st1  = ws;  ws += 128;
  float* wstT = ws;  ws += 16384;     // 64x256 transposed head weights
  float* wT1  = ws;  ws += 20480;     // 32x640

  hipLaunchKernelGGL(k_node0, dim3(1000), dim3(320), 0, stream,
                     x, w0, b0, root0, bias0, w1, b1, root1, s_w, t_w,
                     G0h, h0h, wT1, wstT, st0, st1, out);
  hipLaunchKernelGGL(k_edge0, dim3(2048), dim3(256), 0, stream,
                     ei, ea, G0h, h0h);
  hipLaunchKernelGGL(k_stats<32>, dim3(256), dim3(256), 0, stream, h0h, st0);
  hipLaunchKernelGGL(k_node1, dim3(1000), dim3(320), 0, stream,
                     h0h, st0, g0, be0, wT1, bias1, G1h, h1h);
  hipLaunchKernelGGL(k_edge1, dim3(2048), dim3(256), 0, stream,
                     ei, ea, G1h, h1h);
  hipLaunchKernelGGL(k_stats<64>, dim3(256), dim3(256), 0, stream, h1h, st1);
  hipLaunchKernelGGL(k_head, dim3(500), dim3(256), 0, stream,
                     h1h, st1, g1, be1, wstT, s_b, t_b, batch, out);
}